// Round 1
// baseline (1738.515 us; speedup 1.0000x reference)
//
#include <hip/hip_runtime.h>
#include <cstdint>
#include <cstddef>

typedef uint16_t u16;
typedef __bf16 bf16x8 __attribute__((ext_vector_type(8)));
typedef float f32x4 __attribute__((ext_vector_type(4)));
typedef unsigned short us4 __attribute__((ext_vector_type(4)));

#define NTOK 131072          // B*N = 8*16384
#define SEQN 16384
#define CDIM 128

__device__ __forceinline__ float b2f(u16 u) {
    unsigned int x = ((unsigned int)u) << 16;
    return __builtin_bit_cast(float, x);
}
__device__ __forceinline__ u16 f2b(float f) {
    unsigned int x = __builtin_bit_cast(unsigned int, f);
    unsigned int r = (x + 0x7fffu + ((x >> 16) & 1u)) >> 16;
    return (u16)r;
}

// ---------------- permute (gather rows) : dst[b][j][:] = src[b][idx[b][j]][:]
__global__ __launch_bounds__(256) void gather_rows(const float* __restrict__ src,
                                                   const int* __restrict__ idx,
                                                   float* __restrict__ dst) {
    size_t t = (size_t)blockIdx.x * 256 + threadIdx.x;   // over NTOK*32 float4
    int c4 = (int)(t & 31);
    size_t row = t >> 5;                // b*SEQN + j
    int b = (int)(row >> 14);
    int s = idx[row];
    const float4* sp = reinterpret_cast<const float4*>(src + ((size_t)(b << 14) + s) * CDIM);
    reinterpret_cast<float4*>(dst + row * CDIM)[c4] = sp[c4];
}

// ---------------- unpermute (scatter rows) : dst[b][idx[b][j]][:] = src[b][j][:]
__global__ __launch_bounds__(256) void scatter_rows(const float* __restrict__ src,
                                                    const int* __restrict__ idx,
                                                    float* __restrict__ dst) {
    size_t t = (size_t)blockIdx.x * 256 + threadIdx.x;
    int c4 = (int)(t & 31);
    size_t row = t >> 5;
    int b = (int)(row >> 14);
    int s = idx[row];
    const float4* sp = reinterpret_cast<const float4*>(src + row * CDIM);
    reinterpret_cast<float4*>(dst + ((size_t)(b << 14) + s) * CDIM)[c4] = sp[c4];
}

// ---------------- BN stats: acc[0..127]=sum, acc[128..255]=sumsq
__global__ __launch_bounds__(256) void bn_stats(const float* __restrict__ x,
                                                float* __restrict__ acc) {
    int c = threadIdx.x & 127;
    int half = threadIdx.x >> 7;
    float s = 0.f, s2 = 0.f;
    int j0 = blockIdx.x * 512;
    for (int j = j0 + half; j < j0 + 512; j += 2) {
        float v = x[(size_t)j * CDIM + c];
        s += v; s2 += v * v;
    }
    __shared__ float l1[256], l2[256];
    l1[threadIdx.x] = s; l2[threadIdx.x] = s2;
    __syncthreads();
    if (threadIdx.x < 128) {
        atomicAdd(&acc[c], l1[threadIdx.x] + l1[threadIdx.x + 128]);
        atomicAdd(&acc[128 + c], l2[threadIdx.x] + l2[threadIdx.x + 128]);
    }
}

__global__ void bn_finalize(const float* __restrict__ acc, const float* __restrict__ g,
                            const float* __restrict__ b, float* __restrict__ scsh) {
    int c = threadIdx.x;  // 128 threads
    const float invn = 1.0f / (float)NTOK;
    float mean = acc[c] * invn;
    float var = acc[128 + c] * invn - mean * mean;
    float sc = g[c] * rsqrtf(var + 1e-5f);
    scsh[c] = sc;
    scsh[128 + c] = b[c] - mean * sc;
}

// ---------------- apply BN -> bf16
__global__ __launch_bounds__(256) void bn_apply(const float* __restrict__ x,
                                                const float* __restrict__ scsh,
                                                u16* __restrict__ h) {
    __shared__ float sc[128], sh[128];
    if (threadIdx.x < 128) { sc[threadIdx.x] = scsh[threadIdx.x]; sh[threadIdx.x] = scsh[128 + threadIdx.x]; }
    __syncthreads();
    size_t t = (size_t)blockIdx.x * 256 + threadIdx.x;
    size_t base = t * 4;
    int c = (int)(base & 127);
    float4 v = *reinterpret_cast<const float4*>(x + base);
    us4 o;
    o.x = f2b(v.x * sc[c] + sh[c]);
    o.y = f2b(v.y * sc[c + 1] + sh[c + 1]);
    o.z = f2b(v.z * sc[c + 2] + sh[c + 2]);
    o.w = f2b(v.w * sc[c + 3] + sh[c + 3]);
    *reinterpret_cast<us4*>(h + base) = o;
}

// ---------------- weight transpose+convert: wt[n*K+k] = bf16(w[k*N+n])
__global__ __launch_bounds__(256) void wtrans(const float* __restrict__ w, u16* __restrict__ wt,
                                              int K, int N) {
    int t = blockIdx.x * 256 + threadIdx.x;
    if (t >= K * N) return;
    int n = t % N, k = t / N;
    wt[(size_t)n * K + k] = f2b(w[t]);
}

// ---------------- GEMM: Out[M,N] = A[M,K]_bf16 @ Wt[N,K]_bf16^T   (+relu / +resid)
// wave computes 16 rows x 128 cols; block = 4 waves = 64 rows.
template <int K, bool RELU, bool RESID>
__global__ __launch_bounds__(256) void gemm_k(const u16* __restrict__ A,
                                              const u16* __restrict__ Wt,
                                              float* __restrict__ resid,
                                              u16* __restrict__ outb, int N) {
    int lane = threadIdx.x & 63;
    int wv = threadIdx.x >> 6;
    int row0 = blockIdx.x * 64 + wv * 16;
    int col0 = blockIdx.y * 128;
    int l15 = lane & 15;
    int kg = (lane >> 4) << 3;
    const u16* Ap = A + (size_t)(row0 + l15) * K + kg;
    const u16* Wp = Wt + (size_t)(col0 + l15) * K + kg;
    f32x4 acc[8];
#pragma unroll
    for (int t = 0; t < 8; ++t) acc[t] = (f32x4){0.f, 0.f, 0.f, 0.f};
#pragma unroll
    for (int k0 = 0; k0 < K; k0 += 32) {
        bf16x8 af = *reinterpret_cast<const bf16x8*>((const void*)(Ap + k0));
#pragma unroll
        for (int t = 0; t < 8; ++t) {
            bf16x8 bf = *reinterpret_cast<const bf16x8*>((const void*)(Wp + (size_t)t * 16 * K + k0));
            acc[t] = __builtin_amdgcn_mfma_f32_16x16x32_bf16(af, bf, acc[t], 0, 0, 0);
        }
    }
    int rbase = row0 + ((lane >> 4) << 2);
#pragma unroll
    for (int t = 0; t < 8; ++t) {
        int col = col0 + t * 16 + l15;
#pragma unroll
        for (int r = 0; r < 4; ++r) {
            float v = acc[t][r];
            if (RELU) v = fmaxf(v, 0.f);
            size_t off = (size_t)(rbase + r) * N + col;
            if (RESID) resid[off] += v;
            else outb[off] = f2b(v);
        }
    }
}

// ---------------- windowed attention, one (window, head) per block
__global__ __launch_bounds__(256) void attn_k(const u16* __restrict__ qkv, u16* __restrict__ o) {
    int blk = blockIdx.x;
    int hd = blk & 3;
    int win = (blk >> 2) & 255;
    int b = blk >> 10;
    __shared__ float q[64][37], kk[64][37], vv[64][37];
    __shared__ float P[64][68];
    const u16* base = qkv + ((size_t)((b << 14) + (win << 6))) * 384 + hd * 32;
    for (int idx = threadIdx.x; idx < 2048; idx += 256) {
        int tok = idx >> 5, d = idx & 31;
        const u16* p = base + (size_t)tok * 384 + d;
        q[tok][d] = b2f(p[0]);
        kk[tok][d] = b2f(p[128]);
        vv[tok][d] = b2f(p[256]);
    }
    __syncthreads();
    int row = threadIdx.x >> 2, cg = threadIdx.x & 3;
    const float scale = 0.17677669529663687f;  // 1/sqrt(32)
    float s[16];
    float m = -1e30f;
#pragma unroll
    for (int cc = 0; cc < 16; ++cc) {
        int col = cg * 16 + cc;
        float a = 0.f;
#pragma unroll
        for (int d = 0; d < 32; ++d) a += q[row][d] * kk[col][d];
        s[cc] = a * scale;
        m = fmaxf(m, s[cc]);
    }
    m = fmaxf(m, __shfl_xor(m, 1));
    m = fmaxf(m, __shfl_xor(m, 2));
    float sum = 0.f;
#pragma unroll
    for (int cc = 0; cc < 16; ++cc) { s[cc] = __expf(s[cc] - m); sum += s[cc]; }
    sum += __shfl_xor(sum, 1);
    sum += __shfl_xor(sum, 2);
    float inv = 1.0f / sum;
#pragma unroll
    for (int cc = 0; cc < 16; ++cc) P[row][cg * 16 + cc] = s[cc] * inv;
    __syncthreads();
    float ov[8] = {0.f, 0.f, 0.f, 0.f, 0.f, 0.f, 0.f, 0.f};
    for (int j = 0; j < 64; ++j) {
        float p = P[row][j];
#pragma unroll
        for (int dd = 0; dd < 8; ++dd) ov[dd] += p * vv[j][cg * 8 + dd];
    }
    u16* op = o + ((size_t)((b << 14) + (win << 6) + row)) * CDIM + hd * 32 + cg * 8;
#pragma unroll
    for (int dd = 0; dd < 8; ++dd) op[dd] = f2b(ov[dd]);
}

extern "C" void kernel_launch(void* const* d_in, const int* in_sizes, int n_in,
                              void* d_out, int out_size, void* d_ws, size_t ws_size,
                              hipStream_t stream) {
    const float* x_in = (const float*)d_in[0];
    const float* z_in = (const float*)d_in[1];
    const int* ip1 = (const int*)d_in[2];
    const int* ip2 = (const int*)d_in[3];
    const float* qkv_w = (const float*)d_in[4];
    const float* proj_w = (const float*)d_in[5];
    const float* fc1_w = (const float*)d_in[6];
    const float* fc2_w = (const float*)d_in[7];
    const float* n1g = (const float*)d_in[8];
    const float* n1b = (const float*)d_in[9];
    const float* n2g = (const float*)d_in[10];
    const float* n2b = (const float*)d_in[11];

    char* ws = (char*)d_ws;
    float* xp = (float*)(ws + 0);                       // 67,108,864 B
    u16* qkvb = (u16*)(ws + 67108864);                  // 100,663,296 B
    u16* ob   = (u16*)(ws + 167772160);                 // 33,554,432 B
    u16* rb   = qkvb;                                   // aliases qkv+ob (134,217,728 B)
    u16* hb   = (u16*)(ws + 201326592);                 // 33,554,432 B
    u16* wtb  = (u16*)(ws + 234881024);                 // 786,432 B
    float* stats = (float*)(ws + 235667456);            // 4 acc sets * 256 + scsh 256

    float* out_x = (float*)d_out;
    float* out_z = out_x + (size_t)NTOK * CDIM;

    // zero the BN accumulators (4 sets of 256 floats)
    hipMemsetAsync(stats, 0, 4 * 256 * sizeof(float), stream);
    // z is a pass-through
    hipMemcpyAsync(out_z, z_in, (size_t)NTOK * 3 * sizeof(float),
                   hipMemcpyDeviceToDevice, stream);

    // transpose+convert all weights to bf16 [N][K]
    for (int i = 0; i < 2; ++i) {
        wtrans<<<(128 * 384 + 255) / 256, 256, 0, stream>>>(qkv_w + (size_t)i * 128 * 384,
                                                            wtb + i * 49152, 128, 384);
        wtrans<<<(128 * 128 + 255) / 256, 256, 0, stream>>>(proj_w + (size_t)i * 128 * 128,
                                                            wtb + 98304 + i * 16384, 128, 128);
        wtrans<<<(128 * 512 + 255) / 256, 256, 0, stream>>>(fc1_w + (size_t)i * 128 * 512,
                                                            wtb + 131072 + i * 65536, 128, 512);
        wtrans<<<(512 * 128 + 255) / 256, 256, 0, stream>>>(fc2_w + (size_t)i * 512 * 128,
                                                            wtb + 262144 + i * 65536, 512, 128);
    }

    for (int i = 0; i < 2; ++i) {
        const int* ip = (i == 0) ? ip1 : ip2;
        const float* xsrc = (i == 0) ? x_in : out_x;
        float* acc1 = stats + (i * 2 + 0) * 256;
        float* acc2 = stats + (i * 2 + 1) * 256;
        float* scsh = stats + 4 * 256;
        const u16* wt_qkv = wtb + i * 49152;
        const u16* wt_proj = wtb + 98304 + i * 16384;
        const u16* wt_fc1 = wtb + 131072 + i * 65536;
        const u16* wt_fc2 = wtb + 262144 + i * 65536;

        gather_rows<<<16384, 256, 0, stream>>>(xsrc, ip, xp);
        bn_stats<<<256, 256, 0, stream>>>(xp, acc1);
        bn_finalize<<<1, 128, 0, stream>>>(acc1, n1g + i * 128, n1b + i * 128, scsh);
        bn_apply<<<16384, 256, 0, stream>>>(xp, scsh, hb);
        gemm_k<128, false, false><<<dim3(2048, 3), 256, 0, stream>>>(hb, wt_qkv, nullptr, qkvb, 384);
        attn_k<<<8192, 256, 0, stream>>>(qkvb, ob);
        gemm_k<128, false, true><<<dim3(2048, 1), 256, 0, stream>>>(ob, wt_proj, xp, nullptr, 128);
        bn_stats<<<256, 256, 0, stream>>>(xp, acc2);
        bn_finalize<<<1, 128, 0, stream>>>(acc2, n2g + i * 128, n2b + i * 128, scsh);
        bn_apply<<<16384, 256, 0, stream>>>(xp, scsh, hb);
        gemm_k<128, true, false><<<dim3(2048, 4), 256, 0, stream>>>(hb, wt_fc1, nullptr, rb, 512);
        gemm_k<512, false, true><<<dim3(2048, 1), 256, 0, stream>>>(rb, wt_fc2, xp, nullptr, 128);
        scatter_rows<<<16384, 256, 0, stream>>>(xp, ip, out_x);
    }
}

// Round 2
// 836.503 us; speedup vs baseline: 2.0783x; 2.0783x over previous
//
#include <hip/hip_runtime.h>
#include <cstdint>
#include <cstddef>

typedef uint16_t u16;
typedef __bf16 bf16x8 __attribute__((ext_vector_type(8)));
typedef float f32x4 __attribute__((ext_vector_type(4)));
typedef unsigned short us4 __attribute__((ext_vector_type(4)));
typedef unsigned short us8 __attribute__((ext_vector_type(8)));

#define NTOK 131072          // B*N = 8*16384
#define CDIM 128

__device__ __forceinline__ float b2f(u16 u) {
    unsigned int x = ((unsigned int)u) << 16;
    return __builtin_bit_cast(float, x);
}
__device__ __forceinline__ u16 f2b(float f) {
    unsigned int x = __builtin_bit_cast(unsigned int, f);
    unsigned int r = (x + 0x7fffu + ((x >> 16) & 1u)) >> 16;
    return (u16)r;
}

__device__ __forceinline__ void gload16(const void* g, void* l) {
    __builtin_amdgcn_global_load_lds((const __attribute__((address_space(1))) void*)g,
                                     (__attribute__((address_space(3))) void*)l, 16, 0, 0);
}

// ---------------- BN stats (standalone, used once on x_in; perm-invariant)
__global__ __launch_bounds__(256) void bn_stats(const float* __restrict__ x,
                                                float* __restrict__ acc) {
    int c = threadIdx.x & 127;
    int half = threadIdx.x >> 7;
    float s = 0.f, s2 = 0.f;
    int j0 = blockIdx.x * 512;
    for (int j = j0 + half; j < j0 + 512; j += 2) {
        float v = x[(size_t)j * CDIM + c];
        s += v; s2 += v * v;
    }
    __shared__ float l1[256], l2[256];
    l1[threadIdx.x] = s; l2[threadIdx.x] = s2;
    __syncthreads();
    if (threadIdx.x < 128) {
        atomicAdd(&acc[c], l1[threadIdx.x] + l1[threadIdx.x + 128]);
        atomicAdd(&acc[128 + c], l2[threadIdx.x] + l2[threadIdx.x + 128]);
    }
}

__global__ void bn_finalize(const float* __restrict__ acc, const float* __restrict__ g,
                            const float* __restrict__ b, float* __restrict__ scsh) {
    int c = threadIdx.x;  // 128 threads
    const float invn = 1.0f / (float)NTOK;
    float mean = acc[c] * invn;
    float var = acc[128 + c] * invn - mean * mean;
    float sc = g[c] * rsqrtf(var + 1e-5f);
    scsh[c] = sc;
    scsh[128 + c] = b[c] - mean * sc;
}

// ---------------- gather rows + apply BN -> xp (fp32) and hb (bf16 normalized)
__global__ __launch_bounds__(256) void gather_apply(const float* __restrict__ src,
                                                    const int* __restrict__ idx,
                                                    const float* __restrict__ scsh,
                                                    float* __restrict__ xp,
                                                    u16* __restrict__ hb) {
    __shared__ float sc[128], sh[128];
    if (threadIdx.x < 128) { sc[threadIdx.x] = scsh[threadIdx.x]; sh[threadIdx.x] = scsh[128 + threadIdx.x]; }
    __syncthreads();
    size_t t = (size_t)blockIdx.x * 256 + threadIdx.x;   // NTOK*32 threads
    int c4 = (int)(t & 31) * 4;
    size_t row = t >> 5;
    int b = (int)(row >> 14);
    int s = idx[row];
    float4 v = *reinterpret_cast<const float4*>(src + ((size_t)(b << 14) + s) * CDIM + c4);
    *reinterpret_cast<float4*>(xp + row * CDIM + c4) = v;
    us4 o;
    o.x = f2b(v.x * sc[c4] + sh[c4]);
    o.y = f2b(v.y * sc[c4 + 1] + sh[c4 + 1]);
    o.z = f2b(v.z * sc[c4 + 2] + sh[c4 + 2]);
    o.w = f2b(v.w * sc[c4 + 3] + sh[c4 + 3]);
    *reinterpret_cast<us4*>(hb + row * CDIM + c4) = o;
}

// ---------------- apply BN -> bf16 (for bn2)
__global__ __launch_bounds__(256) void bn_apply(const float* __restrict__ x,
                                                const float* __restrict__ scsh,
                                                u16* __restrict__ h) {
    __shared__ float sc[128], sh[128];
    if (threadIdx.x < 128) { sc[threadIdx.x] = scsh[threadIdx.x]; sh[threadIdx.x] = scsh[128 + threadIdx.x]; }
    __syncthreads();
    size_t t = (size_t)blockIdx.x * 256 + threadIdx.x;
    size_t base = t * 4;
    int c = (int)(base & 127);
    float4 v = *reinterpret_cast<const float4*>(x + base);
    us4 o;
    o.x = f2b(v.x * sc[c] + sh[c]);
    o.y = f2b(v.y * sc[c + 1] + sh[c + 1]);
    o.z = f2b(v.z * sc[c + 2] + sh[c + 2]);
    o.w = f2b(v.w * sc[c + 3] + sh[c + 3]);
    *reinterpret_cast<us4*>(h + base) = o;
}

// ---------------- weight transpose+convert: wt[n*K+k] = bf16(w[k*N+n])
__global__ __launch_bounds__(256) void wtrans(const float* __restrict__ w, u16* __restrict__ wt,
                                              int K, int N) {
    int t = blockIdx.x * 256 + threadIdx.x;
    if (t >= K * N) return;
    int n = t % N, k = t / N;
    wt[(size_t)n * K + k] = f2b(w[t]);
}

// ---------------- GEMM: Out[M,N] = A[M,K]_bf16 @ Wt[N,K]_bf16^T
// 128x128 tile, LDS-staged (global_load_lds w16, XOR-swizzled), 4 waves -> 64x64 each.
// MODE 0: store bf16. MODE 1: relu + store bf16.
// MODE 2: resid += (fp32, in place) + col stats atomics.
// MODE 3: v = resid[row]+acc, scatter-write outf[(b<<14)+ip[row]] (+ stats if stat!=null).
template <int K, int MODE>
__global__ __launch_bounds__(256, 2) void gemm2(const u16* __restrict__ A,
                                                const u16* __restrict__ Wt,
                                                u16* __restrict__ outb,
                                                float* __restrict__ resid,
                                                float* __restrict__ outf,
                                                const int* __restrict__ ip,
                                                float* __restrict__ stat, int N) {
    __shared__ u16 As[128 * 128];
    __shared__ u16 Bs[128 * 128];
    int lane = threadIdx.x & 63;
    int wv = threadIdx.x >> 6;
    int l15 = lane & 15;
    int hi = lane >> 4;
    int m0 = blockIdx.x * 128;
    int n0 = blockIdx.y * 128;
    int wr = (wv >> 1) << 6;
    int wc = (wv & 1) << 6;
    f32x4 acc[4][4];
#pragma unroll
    for (int i = 0; i < 4; ++i)
#pragma unroll
        for (int j = 0; j < 4; ++j) acc[i][j] = (f32x4){0.f, 0.f, 0.f, 0.f};

    int crow = hi;                 // lane>>4 : row within 4-row chunk
    int cbyte = l15 * 16;          // byte within 256B row
    for (int kk = 0; kk < K; kk += 128) {
        if (kk) __syncthreads();
#pragma unroll
        for (int c = 0; c < 8; ++c) {
            int cc = wv * 8 + c;            // chunk 0..31
            int r = cc * 4 + crow;          // tile row 0..127
            int bofs = cbyte ^ ((r & 7) << 4);
            gload16(A + (size_t)(m0 + r) * K + kk + (bofs >> 1), (char*)As + cc * 1024);
            gload16(Wt + (size_t)(n0 + r) * K + kk + (bofs >> 1), (char*)Bs + cc * 1024);
        }
        __syncthreads();
#pragma unroll
        for (int ks = 0; ks < 4; ++ks) {
            bf16x8 af[4], bf[4];
#pragma unroll
            for (int q = 0; q < 4; ++q) {
                int row = wr + q * 16 + l15;
                int bo = (ks * 64 + hi * 16) ^ ((row & 7) << 4);
                af[q] = *(const bf16x8*)((const char*)As + row * 256 + bo);
                int rowb = wc + q * 16 + l15;
                int bob = (ks * 64 + hi * 16) ^ ((rowb & 7) << 4);
                bf[q] = *(const bf16x8*)((const char*)Bs + rowb * 256 + bob);
            }
#pragma unroll
            for (int q = 0; q < 4; ++q)
#pragma unroll
                for (int n = 0; n < 4; ++n)
                    acc[q][n] = __builtin_amdgcn_mfma_f32_16x16x32_bf16(af[q], bf[n], acc[q][n], 0, 0, 0);
        }
    }

    if (MODE <= 1) {
#pragma unroll
        for (int q = 0; q < 4; ++q)
#pragma unroll
            for (int n = 0; n < 4; ++n)
#pragma unroll
                for (int r = 0; r < 4; ++r) {
                    float v = acc[q][n][r];
                    if (MODE == 1) v = fmaxf(v, 0.f);
                    int row = m0 + wr + q * 16 + hi * 4 + r;
                    int col = n0 + wc + n * 16 + l15;
                    outb[(size_t)row * N + col] = f2b(v);
                }
    } else {
        bool do_stat = (MODE == 2) || (stat != nullptr);
        float sm[4], sq[4];
#pragma unroll
        for (int n = 0; n < 4; ++n) { sm[n] = 0.f; sq[n] = 0.f; }
#pragma unroll
        for (int q = 0; q < 4; ++q)
#pragma unroll
            for (int n = 0; n < 4; ++n)
#pragma unroll
                for (int r = 0; r < 4; ++r) {
                    int row = m0 + wr + q * 16 + hi * 4 + r;
                    int col = wc + n * 16 + l15;
                    size_t off = (size_t)row * 128 + col;
                    float v = resid[off] + acc[q][n][r];
                    if (MODE == 2) {
                        resid[off] = v;
                    } else {
                        int b = row >> 14;
                        int orow = (b << 14) + ip[row];
                        outf[(size_t)orow * 128 + col] = v;
                    }
                    if (do_stat) { sm[n] += v; sq[n] += v * v; }
                }
        if (do_stat) {
#pragma unroll
            for (int n = 0; n < 4; ++n) {
                sm[n] += __shfl_xor(sm[n], 16); sm[n] += __shfl_xor(sm[n], 32);
                sq[n] += __shfl_xor(sq[n], 16); sq[n] += __shfl_xor(sq[n], 32);
            }
            if (lane < 16) {
#pragma unroll
                for (int n = 0; n < 4; ++n) {
                    int col = wc + n * 16 + l15;
                    atomicAdd(&stat[col], sm[n]);
                    atomicAdd(&stat[128 + col], sq[n]);
                }
            }
        }
    }
}

// ---------------- MFMA windowed attention: one window/block, wave = head
__global__ __launch_bounds__(256, 2) void attn_k(const u16* __restrict__ qkv,
                                                 u16* __restrict__ ob) {
    __shared__ u16 vt[4][32 * 72];   // V^T per head: [dim][tok], pad 72
    __shared__ u16 P[4][64 * 72];    // per-wave P matrix [q][k], pad 72
    int lane = threadIdx.x & 63;
    int wv = threadIdx.x >> 6;
    int l15 = lane & 15, hi = lane >> 4;
    size_t tokbase = (size_t)blockIdx.x * 64;

    // stage V^T (all threads cooperate across heads)
    int tid = threadIdx.x;
#pragma unroll
    for (int p = 0; p < 4; ++p) {
        int e = p * 2048 + tid * 8;
        int tok = e >> 7, d = e & 127;
        int h2 = d >> 5, dd = d & 31;
        us8 v = *(const us8*)(qkv + (tokbase + tok) * 384 + 256 + d);
#pragma unroll
        for (int j = 0; j < 8; ++j) vt[h2][(dd + j) * 72 + tok] = v[j];
    }

    // Q,K fragments straight from global (head = wv)
    const u16* base = qkv + tokbase * 384 + wv * 32;
    bf16x8 qf[4], kf[4];
#pragma unroll
    for (int t = 0; t < 4; ++t) {
        qf[t] = *(const bf16x8*)(base + (size_t)(t * 16 + l15) * 384 + hi * 8);
        kf[t] = *(const bf16x8*)(base + (size_t)(t * 16 + l15) * 384 + 128 + hi * 8);
    }
    f32x4 s[4][4];
#pragma unroll
    for (int i = 0; i < 4; ++i)
#pragma unroll
        for (int j = 0; j < 4; ++j) s[i][j] = (f32x4){0.f, 0.f, 0.f, 0.f};
#pragma unroll
    for (int qi = 0; qi < 4; ++qi)
#pragma unroll
        for (int ki = 0; ki < 4; ++ki)
            s[qi][ki] = __builtin_amdgcn_mfma_f32_16x16x32_bf16(qf[qi], kf[ki], s[qi][ki], 0, 0, 0);

    const float scale = 0.17677669529663687f;  // 1/sqrt(32)
    float inv[4][4];
#pragma unroll
    for (int qi = 0; qi < 4; ++qi) {
#pragma unroll
        for (int r = 0; r < 4; ++r) {
            float v0 = s[qi][0][r] * scale, v1 = s[qi][1][r] * scale;
            float v2 = s[qi][2][r] * scale, v3 = s[qi][3][r] * scale;
            float m = fmaxf(fmaxf(v0, v1), fmaxf(v2, v3));
            m = fmaxf(m, __shfl_xor(m, 1)); m = fmaxf(m, __shfl_xor(m, 2));
            m = fmaxf(m, __shfl_xor(m, 4)); m = fmaxf(m, __shfl_xor(m, 8));
            float p0 = __expf(v0 - m), p1 = __expf(v1 - m);
            float p2 = __expf(v2 - m), p3 = __expf(v3 - m);
            float sum = p0 + p1 + p2 + p3;
            sum += __shfl_xor(sum, 1); sum += __shfl_xor(sum, 2);
            sum += __shfl_xor(sum, 4); sum += __shfl_xor(sum, 8);
            inv[qi][r] = 1.0f / sum;
            int row = qi * 16 + hi * 4 + r;
            P[wv][row * 72 + l15] = f2b(p0);
            P[wv][row * 72 + 16 + l15] = f2b(p1);
            P[wv][row * 72 + 32 + l15] = f2b(p2);
            P[wv][row * 72 + 48 + l15] = f2b(p3);
        }
    }
    __syncthreads();

    f32x4 o[4][2];
#pragma unroll
    for (int i = 0; i < 4; ++i)
#pragma unroll
        for (int j = 0; j < 2; ++j) o[i][j] = (f32x4){0.f, 0.f, 0.f, 0.f};
#pragma unroll
    for (int ks = 0; ks < 2; ++ks) {
        bf16x8 pa[4], vb[2];
#pragma unroll
        for (int qi = 0; qi < 4; ++qi)
            pa[qi] = *(const bf16x8*)&P[wv][(qi * 16 + l15) * 72 + ks * 32 + hi * 8];
#pragma unroll
        for (int ni = 0; ni < 2; ++ni)
            vb[ni] = *(const bf16x8*)&vt[wv][(ni * 16 + l15) * 72 + ks * 32 + hi * 8];
#pragma unroll
        for (int qi = 0; qi < 4; ++qi)
#pragma unroll
            for (int ni = 0; ni < 2; ++ni)
                o[qi][ni] = __builtin_amdgcn_mfma_f32_16x16x32_bf16(pa[qi], vb[ni], o[qi][ni], 0, 0, 0);
    }
#pragma unroll
    for (int qi = 0; qi < 4; ++qi)
#pragma unroll
        for (int ni = 0; ni < 2; ++ni)
#pragma unroll
            for (int r = 0; r < 4; ++r) {
                float v = o[qi][ni][r] * inv[qi][r];
                ob[(tokbase + qi * 16 + hi * 4 + r) * 128 + wv * 32 + ni * 16 + l15] = f2b(v);
            }
}

extern "C" void kernel_launch(void* const* d_in, const int* in_sizes, int n_in,
                              void* d_out, int out_size, void* d_ws, size_t ws_size,
                              hipStream_t stream) {
    const float* x_in = (const float*)d_in[0];
    const float* z_in = (const float*)d_in[1];
    const int* ip1 = (const int*)d_in[2];
    const int* ip2 = (const int*)d_in[3];
    const float* qkv_w = (const float*)d_in[4];
    const float* proj_w = (const float*)d_in[5];
    const float* fc1_w = (const float*)d_in[6];
    const float* fc2_w = (const float*)d_in[7];
    const float* n1g = (const float*)d_in[8];
    const float* n1b = (const float*)d_in[9];
    const float* n2g = (const float*)d_in[10];
    const float* n2b = (const float*)d_in[11];

    char* ws = (char*)d_ws;
    float* xp = (float*)(ws + 0);                       // 67,108,864 B
    u16* qkvb = (u16*)(ws + 67108864);                  // 100,663,296 B
    u16* ob   = (u16*)(ws + 167772160);                 // 33,554,432 B
    u16* rb   = qkvb;                                   // aliases qkv+ob (134,217,728 B)
    u16* hb   = (u16*)(ws + 201326592);                 // 33,554,432 B
    u16* wtb  = (u16*)(ws + 234881024);                 // 786,432 B
    float* stats = (float*)(ws + 235667456);            // 4 acc sets (256) + scsh 256
    float* scsh = stats + 1024;

    float* out_x = (float*)d_out;
    float* out_z = out_x + (size_t)NTOK * CDIM;

    hipMemsetAsync(stats, 0, 4 * 256 * sizeof(float), stream);
    hipMemcpyAsync(out_z, z_in, (size_t)NTOK * 3 * sizeof(float),
                   hipMemcpyDeviceToDevice, stream);

    for (int i = 0; i < 2; ++i) {
        wtrans<<<(128 * 384 + 255) / 256, 256, 0, stream>>>(qkv_w + (size_t)i * 128 * 384,
                                                            wtb + i * 49152, 128, 384);
        wtrans<<<(128 * 128 + 255) / 256, 256, 0, stream>>>(proj_w + (size_t)i * 128 * 128,
                                                            wtb + 98304 + i * 16384, 128, 128);
        wtrans<<<(128 * 512 + 255) / 256, 256, 0, stream>>>(fc1_w + (size_t)i * 128 * 512,
                                                            wtb + 131072 + i * 65536, 128, 512);
        wtrans<<<(512 * 128 + 255) / 256, 256, 0, stream>>>(fc2_w + (size_t)i * 512 * 128,
                                                            wtb + 262144 + i * 65536, 512, 128);
    }

    bn_stats<<<256, 256, 0, stream>>>(x_in, stats + 0);   // bn1 stats, block 0 (perm-invariant)

    for (int i = 0; i < 2; ++i) {
        const int* ip = (i == 0) ? ip1 : ip2;
        const float* xsrc = (i == 0) ? x_in : out_x;
        float* acc1 = stats + (i == 0 ? 0 : 512);         // block1 bn1 filled by fc2 epilogue
        float* acc2 = stats + (i == 0 ? 256 : 768);
        const u16* wt_qkv = wtb + i * 49152;
        const u16* wt_proj = wtb + 98304 + i * 16384;
        const u16* wt_fc1 = wtb + 131072 + i * 65536;
        const u16* wt_fc2 = wtb + 262144 + i * 65536;

        bn_finalize<<<1, 128, 0, stream>>>(acc1, n1g + i * 128, n1b + i * 128, scsh);
        gather_apply<<<16384, 256, 0, stream>>>(xsrc, ip, scsh, xp, hb);
        gemm2<128, 0><<<dim3(1024, 3), 256, 0, stream>>>(hb, wt_qkv, qkvb, nullptr, nullptr,
                                                         nullptr, nullptr, 384);
        attn_k<<<2048, 256, 0, stream>>>(qkvb, ob);
        gemm2<128, 2><<<dim3(1024, 1), 256, 0, stream>>>(ob, wt_proj, nullptr, xp, nullptr,
                                                         nullptr, acc2, 128);
        bn_finalize<<<1, 128, 0, stream>>>(acc2, n2g + i * 128, n2b + i * 128, scsh);
        bn_apply<<<16384, 256, 0, stream>>>(xp, scsh, hb);
        gemm2<128, 1><<<dim3(1024, 4), 256, 0, stream>>>(hb, wt_fc1, rb, nullptr, nullptr,
                                                         nullptr, nullptr, 512);
        gemm2<512, 3><<<dim3(1024, 1), 256, 0, stream>>>(rb, wt_fc2, nullptr, xp, out_x, ip,
                                                         (i == 0) ? (stats + 512) : nullptr, 128);
    }
}

// Round 3
// 499.104 us; speedup vs baseline: 3.4833x; 1.6760x over previous
//
#include <hip/hip_runtime.h>
#include <cstdint>
#include <cstddef>

typedef uint16_t u16;
typedef __bf16 bf16x8 __attribute__((ext_vector_type(8)));
typedef float f32x4 __attribute__((ext_vector_type(4)));
typedef unsigned short us4 __attribute__((ext_vector_type(4)));

#define NTOK 131072          // B*N = 8*16384
#define CDIM 128
#define MFMA __builtin_amdgcn_mfma_f32_16x16x32_bf16

__device__ __forceinline__ u16 f2b(float f) {
    unsigned int x = __builtin_bit_cast(unsigned int, f);
    unsigned int r = (x + 0x7fffu + ((x >> 16) & 1u)) >> 16;
    return (u16)r;
}

__device__ __forceinline__ us4 pack_bn4(float4 v, const float* sc, const float* sh, int c) {
    us4 o;
    o.x = f2b(v.x * sc[c] + sh[c]);
    o.y = f2b(v.y * sc[c + 1] + sh[c + 1]);
    o.z = f2b(v.z * sc[c + 2] + sh[c + 2]);
    o.w = f2b(v.w * sc[c + 3] + sh[c + 3]);
    return o;
}

// ---------------- initial BN stats on x_in (vectorized, 4-way spread atomics)
__global__ __launch_bounds__(256) void bn_init(const float* __restrict__ x,
                                               float* __restrict__ acc) {
    int tid = threadIdx.x;
    int c4 = tid & 31;          // float4 column group
    int ro = tid >> 5;          // 0..7 row sub-offset
    float4 s = {0.f, 0.f, 0.f, 0.f}, s2 = {0.f, 0.f, 0.f, 0.f};
    size_t base = ((size_t)blockIdx.x * 128 + ro) * 128 + c4 * 4;
#pragma unroll
    for (int it = 0; it < 16; ++it) {
        float4 v = *(const float4*)(x + base + (size_t)it * 1024);
        s.x += v.x; s.y += v.y; s.z += v.z; s.w += v.w;
        s2.x += v.x * v.x; s2.y += v.y * v.y; s2.z += v.z * v.z; s2.w += v.w * v.w;
    }
    __shared__ float4 a1[256], a2[256];
    a1[tid] = s; a2[tid] = s2;
    __syncthreads();
    if (tid < 128) {
        int col4 = tid >> 2, comp = tid & 3;
        float t1 = 0.f, t2 = 0.f;
#pragma unroll
        for (int r = 0; r < 8; ++r) {
            t1 += a1[r * 32 + col4][comp];
            t2 += a2[r * 32 + col4][comp];
        }
        float* st = acc + (blockIdx.x & 3) * 256;
        atomicAdd(st + tid, t1);
        atomicAdd(st + 128 + tid, t2);
    }
}

// ---------------- finalize: sum 4 copies, produce scale/shift
__global__ void bn_finalize(const float* __restrict__ acc, const float* __restrict__ g,
                            const float* __restrict__ b, float* __restrict__ scsh) {
    int c = threadIdx.x;  // 128 threads
    const float invn = 1.0f / (float)NTOK;
    float s = acc[c] + acc[256 + c] + acc[512 + c] + acc[768 + c];
    float q = acc[128 + c] + acc[384 + c] + acc[640 + c] + acc[896 + c];
    float mean = s * invn;
    float var = q * invn - mean * mean;
    float sc = g[c] * rsqrtf(var + 1e-5f);
    scsh[c] = sc;
    scsh[128 + c] = b[c] - mean * sc;
}

// ---------------- weight transpose+convert: wt[n*K+k] = bf16(w[k*N+n])
__global__ __launch_bounds__(256) void wtrans(const float* __restrict__ w, u16* __restrict__ wt,
                                              int K, int N) {
    int t = blockIdx.x * 256 + threadIdx.x;
    if (t >= K * N) return;
    int n = t % N, k = t / N;
    wt[(size_t)n * K + k] = f2b(w[t]);
}

// ---------------- fused: gather+BN1+QKV+attn+proj+resid+BN2stats. One 64-token window/block.
__global__ __launch_bounds__(256, 2) void attn_fused(
    const float* __restrict__ xsrc, float* __restrict__ xdst,
    const int* __restrict__ ip, const float* __restrict__ scsh,
    const u16* __restrict__ wq, const u16* __restrict__ wp,
    float* __restrict__ stat)
{
    __shared__ u16 hsh[64 * 128];      // h (BN'd input), later o — rows 256B, XOR-swizzled
    __shared__ u16 qkp[4][5120];       // per head: q[64][40] | k[64][40]; later P[64][72]
    __shared__ u16 vt[4][32 * 72];     // per head V^T [32 d][72 tok]
    __shared__ float sc[128], sh[128];
    __shared__ int ipl[64];

    int tid = threadIdx.x;
    int lane = tid & 63, wv = tid >> 6;
    int l15 = lane & 15, hi = lane >> 4;
    int b = blockIdx.x >> 8;

    if (tid < 128) { sc[tid] = scsh[tid]; sh[tid] = scsh[128 + tid]; }
    if (tid < 64) ipl[tid] = ip[blockIdx.x * 64 + tid];
    __syncthreads();

    // ---- stage h = BN1(x[ip rows]) -> hsh (swizzled)
    int c4 = tid & 31;
#pragma unroll
    for (int p = 0; p < 8; ++p) {
        int row = p * 8 + (tid >> 5);
        int grow = (b << 14) + ipl[row];
        float4 v = *(const float4*)(xsrc + (size_t)grow * 128 + c4 * 4);
        us4 o = pack_bn4(v, sc, sh, c4 * 4);
        int byte = (c4 * 8) ^ ((row & 7) << 4);
        *(us4*)((char*)hsh + row * 256 + byte) = o;
    }
    __syncthreads();

    // ---- QKV GEMM: out 64 x 96 per wave (head = wv); B-frags from L2
    int nrow[6];
#pragma unroll
    for (int nt = 0; nt < 6; ++nt) nrow[nt] = (nt >> 1) * 128 + wv * 32 + (nt & 1) * 16;
    f32x4 acc[4][6];
#pragma unroll
    for (int q = 0; q < 4; ++q)
#pragma unroll
        for (int nt = 0; nt < 6; ++nt) acc[q][nt] = (f32x4){0.f, 0.f, 0.f, 0.f};
#pragma unroll
    for (int ks = 0; ks < 4; ++ks) {
        bf16x8 af[4];
#pragma unroll
        for (int q = 0; q < 4; ++q) {
            int row = q * 16 + l15;
            int byte = (ks * 64 + hi * 16) ^ ((row & 7) << 4);
            af[q] = *(const bf16x8*)((const char*)hsh + row * 256 + byte);
        }
#pragma unroll
        for (int nt = 0; nt < 6; ++nt) {
            bf16x8 bf = *(const bf16x8*)(wq + (size_t)(nrow[nt] + l15) * 128 + ks * 32 + hi * 8);
#pragma unroll
            for (int q = 0; q < 4; ++q)
                acc[q][nt] = MFMA(af[q], bf, acc[q][nt], 0, 0, 0);
        }
    }

    // ---- spill q,k (row-major pad 40) and v (transposed pad 72) to this wave's LDS
    u16* qh = &qkp[wv][0];
    u16* kh = qh + 2560;
    u16* vh = &vt[wv][0];
#pragma unroll
    for (int nt = 0; nt < 6; ++nt)
#pragma unroll
        for (int q = 0; q < 4; ++q)
#pragma unroll
            for (int r = 0; r < 4; ++r) {
                int tok = q * 16 + hi * 4 + r;
                int d = (nt & 1) * 16 + l15;
                u16 val = f2b(acc[q][nt][r]);
                if (nt < 2) qh[tok * 40 + d] = val;
                else if (nt < 4) kh[tok * 40 + d] = val;
                else vh[d * 72 + tok] = val;
            }

    // ---- QK^T (K=32, single step)
    bf16x8 qa[4], kb[4];
#pragma unroll
    for (int t = 0; t < 4; ++t) {
        qa[t] = *(const bf16x8*)(qh + (t * 16 + l15) * 40 + hi * 8);
        kb[t] = *(const bf16x8*)(kh + (t * 16 + l15) * 40 + hi * 8);
    }
    f32x4 s[4][4];
#pragma unroll
    for (int i = 0; i < 4; ++i)
#pragma unroll
        for (int j = 0; j < 4; ++j) s[i][j] = (f32x4){0.f, 0.f, 0.f, 0.f};
#pragma unroll
    for (int qi = 0; qi < 4; ++qi)
#pragma unroll
        for (int ki = 0; ki < 4; ++ki)
            s[qi][ki] = MFMA(qa[qi], kb[ki], s[qi][ki], 0, 0, 0);

    // ---- softmax (row = q token), write P bf16 over q/k LDS region (same wave only)
    const float scale = 0.17677669529663687f;  // 1/sqrt(32)
    float inv[4][4];
    u16* P = &qkp[wv][0];
#pragma unroll
    for (int qi = 0; qi < 4; ++qi) {
#pragma unroll
        for (int r = 0; r < 4; ++r) {
            float v0 = s[qi][0][r] * scale, v1 = s[qi][1][r] * scale;
            float v2 = s[qi][2][r] * scale, v3 = s[qi][3][r] * scale;
            float m = fmaxf(fmaxf(v0, v1), fmaxf(v2, v3));
            m = fmaxf(m, __shfl_xor(m, 1)); m = fmaxf(m, __shfl_xor(m, 2));
            m = fmaxf(m, __shfl_xor(m, 4)); m = fmaxf(m, __shfl_xor(m, 8));
            float p0 = __expf(v0 - m), p1 = __expf(v1 - m);
            float p2 = __expf(v2 - m), p3 = __expf(v3 - m);
            float sum = p0 + p1 + p2 + p3;
            sum += __shfl_xor(sum, 1); sum += __shfl_xor(sum, 2);
            sum += __shfl_xor(sum, 4); sum += __shfl_xor(sum, 8);
            inv[qi][r] = 1.0f / sum;
            int row = qi * 16 + hi * 4 + r;
            P[row * 72 + l15] = f2b(p0);
            P[row * 72 + 16 + l15] = f2b(p1);
            P[row * 72 + 32 + l15] = f2b(p2);
            P[row * 72 + 48 + l15] = f2b(p3);
        }
    }

    // ---- PV
    f32x4 o[4][2];
#pragma unroll
    for (int i = 0; i < 4; ++i)
#pragma unroll
        for (int j = 0; j < 2; ++j) o[i][j] = (f32x4){0.f, 0.f, 0.f, 0.f};
#pragma unroll
    for (int ks = 0; ks < 2; ++ks) {
        bf16x8 pa[4], vb[2];
#pragma unroll
        for (int qi = 0; qi < 4; ++qi)
            pa[qi] = *(const bf16x8*)(P + (qi * 16 + l15) * 72 + ks * 32 + hi * 8);
#pragma unroll
        for (int nt = 0; nt < 2; ++nt)
            vb[nt] = *(const bf16x8*)(vh + (nt * 16 + l15) * 72 + ks * 32 + hi * 8);
#pragma unroll
        for (int qi = 0; qi < 4; ++qi)
#pragma unroll
            for (int nt = 0; nt < 2; ++nt)
                o[qi][nt] = MFMA(pa[qi], vb[nt], o[qi][nt], 0, 0, 0);
    }

    // ---- write o (bf16, swizzled) into hsh (h is dead; barrier to ensure all waves done with h)
    __syncthreads();
#pragma unroll
    for (int qi = 0; qi < 4; ++qi)
#pragma unroll
        for (int nt = 0; nt < 2; ++nt)
#pragma unroll
            for (int r = 0; r < 4; ++r) {
                int tok = qi * 16 + hi * 4 + r;
                int col = wv * 32 + nt * 16 + l15;
                int byte = (col * 2) ^ ((tok & 7) << 4);
                *(u16*)((char*)hsh + tok * 256 + byte) = f2b(o[qi][nt][r] * inv[qi][r]);
            }
    __syncthreads();

    // ---- proj: out 64 x 32 per wave (cols wv*32..), + residual + BN2 stats
    f32x4 pacc[4][2];
#pragma unroll
    for (int i = 0; i < 4; ++i)
#pragma unroll
        for (int j = 0; j < 2; ++j) pacc[i][j] = (f32x4){0.f, 0.f, 0.f, 0.f};
#pragma unroll
    for (int ks = 0; ks < 4; ++ks) {
        bf16x8 af[4];
#pragma unroll
        for (int q = 0; q < 4; ++q) {
            int row = q * 16 + l15;
            int byte = (ks * 64 + hi * 16) ^ ((row & 7) << 4);
            af[q] = *(const bf16x8*)((const char*)hsh + row * 256 + byte);
        }
#pragma unroll
        for (int nt = 0; nt < 2; ++nt) {
            bf16x8 bf = *(const bf16x8*)(wp + (size_t)(wv * 32 + nt * 16 + l15) * 128 + ks * 32 + hi * 8);
#pragma unroll
            for (int q = 0; q < 4; ++q)
                pacc[q][nt] = MFMA(af[q], bf, pacc[q][nt], 0, 0, 0);
        }
    }
    float cs[2] = {0.f, 0.f}, cq[2] = {0.f, 0.f};
#pragma unroll
    for (int qi = 0; qi < 4; ++qi)
#pragma unroll
        for (int r = 0; r < 4; ++r) {
            int tok = qi * 16 + hi * 4 + r;
            size_t grow = (size_t)((b << 14) + ipl[tok]) * 128;
#pragma unroll
            for (int nt = 0; nt < 2; ++nt) {
                int col = wv * 32 + nt * 16 + l15;
                float v = pacc[qi][nt][r] + xsrc[grow + col];
                xdst[grow + col] = v;
                cs[nt] += v; cq[nt] += v * v;
            }
        }
#pragma unroll
    for (int nt = 0; nt < 2; ++nt) {
        cs[nt] += __shfl_xor(cs[nt], 16); cs[nt] += __shfl_xor(cs[nt], 32);
        cq[nt] += __shfl_xor(cq[nt], 16); cq[nt] += __shfl_xor(cq[nt], 32);
    }
    if (lane < 16) {
        float* st = stat + (blockIdx.x & 3) * 256;
#pragma unroll
        for (int nt = 0; nt < 2; ++nt) {
            int col = wv * 32 + nt * 16 + l15;
            atomicAdd(st + col, cs[nt]);
            atomicAdd(st + 128 + col, cq[nt]);
        }
    }
}

// ---------------- fused: BN2+fc1+relu+fc2+resid (+next BN1 stats). 128-row tile/block.
__global__ __launch_bounds__(256, 2) void mlp_fused(
    const float* __restrict__ xsrc, float* __restrict__ xdst,
    const float* __restrict__ scsh,
    const u16* __restrict__ w1, const u16* __restrict__ w2,
    float* __restrict__ stat)
{
    __shared__ u16 hb[128 * 128];   // BN'd input, swizzled
    __shared__ u16 hc[128 * 128];   // hidden chunk, swizzled
    __shared__ float sc[128], sh[128];
    int tid = threadIdx.x, lane = tid & 63, wv = tid >> 6;
    int l15 = lane & 15, hi = lane >> 4;
    int m0 = blockIdx.x * 128;
    if (tid < 128) { sc[tid] = scsh[tid]; sh[tid] = scsh[128 + tid]; }
    __syncthreads();

    int c4 = tid & 31;
#pragma unroll
    for (int p = 0; p < 16; ++p) {
        int row = p * 8 + (tid >> 5);
        float4 v = *(const float4*)(xsrc + (size_t)(m0 + row) * 128 + c4 * 4);
        us4 o = pack_bn4(v, sc, sh, c4 * 4);
        int byte = (c4 * 8) ^ ((row & 7) << 4);
        *(us4*)((char*)hb + row * 256 + byte) = o;
    }
    __syncthreads();

    int wr = (wv >> 1) * 64, wc = (wv & 1) * 64;
    f32x4 acc2[4][4];
#pragma unroll
    for (int i = 0; i < 4; ++i)
#pragma unroll
        for (int j = 0; j < 4; ++j) acc2[i][j] = (f32x4){0.f, 0.f, 0.f, 0.f};

    for (int c = 0; c < 4; ++c) {
        f32x4 acc1[4][4];
#pragma unroll
        for (int i = 0; i < 4; ++i)
#pragma unroll
            for (int j = 0; j < 4; ++j) acc1[i][j] = (f32x4){0.f, 0.f, 0.f, 0.f};
#pragma unroll
        for (int ks = 0; ks < 4; ++ks) {
            bf16x8 af[4];
#pragma unroll
            for (int q = 0; q < 4; ++q) {
                int row = wr + q * 16 + l15;
                int byte = (ks * 64 + hi * 16) ^ ((row & 7) << 4);
                af[q] = *(const bf16x8*)((const char*)hb + row * 256 + byte);
            }
#pragma unroll
            for (int nt = 0; nt < 4; ++nt) {
                bf16x8 bf = *(const bf16x8*)(w1 + (size_t)(c * 128 + wc + nt * 16 + l15) * 128 + ks * 32 + hi * 8);
#pragma unroll
                for (int q = 0; q < 4; ++q)
                    acc1[q][nt] = MFMA(af[q], bf, acc1[q][nt], 0, 0, 0);
            }
        }
        __syncthreads();   // previous GEMM2 reads of hc complete
#pragma unroll
        for (int q = 0; q < 4; ++q)
#pragma unroll
            for (int nt = 0; nt < 4; ++nt)
#pragma unroll
                for (int r = 0; r < 4; ++r) {
                    int row = wr + q * 16 + hi * 4 + r;
                    int col = wc + nt * 16 + l15;
                    int byte = (col * 2) ^ ((row & 7) << 4);
                    *(u16*)((char*)hc + row * 256 + byte) = f2b(fmaxf(acc1[q][nt][r], 0.f));
                }
        __syncthreads();
#pragma unroll
        for (int ks = 0; ks < 4; ++ks) {
            bf16x8 af[4];
#pragma unroll
            for (int q = 0; q < 4; ++q) {
                int row = wr + q * 16 + l15;
                int byte = (ks * 64 + hi * 16) ^ ((row & 7) << 4);
                af[q] = *(const bf16x8*)((const char*)hc + row * 256 + byte);
            }
#pragma unroll
            for (int nt = 0; nt < 4; ++nt) {
                bf16x8 bf = *(const bf16x8*)(w2 + (size_t)(wc + nt * 16 + l15) * 512 + c * 128 + ks * 32 + hi * 8);
#pragma unroll
                for (int q = 0; q < 4; ++q)
                    acc2[q][nt] = MFMA(af[q], bf, acc2[q][nt], 0, 0, 0);
            }
        }
    }

    float cs[4] = {0.f, 0.f, 0.f, 0.f}, cq[4] = {0.f, 0.f, 0.f, 0.f};
#pragma unroll
    for (int q = 0; q < 4; ++q)
#pragma unroll
        for (int r = 0; r < 4; ++r) {
            size_t row = (size_t)(m0 + wr + q * 16 + hi * 4 + r) * 128;
#pragma unroll
            for (int nt = 0; nt < 4; ++nt) {
                int col = wc + nt * 16 + l15;
                float v = acc2[q][nt][r] + xsrc[row + col];
                xdst[row + col] = v;
                cs[nt] += v; cq[nt] += v * v;
            }
        }
    if (stat) {
#pragma unroll
        for (int nt = 0; nt < 4; ++nt) {
            cs[nt] += __shfl_xor(cs[nt], 16); cs[nt] += __shfl_xor(cs[nt], 32);
            cq[nt] += __shfl_xor(cq[nt], 16); cq[nt] += __shfl_xor(cq[nt], 32);
        }
        if (lane < 16) {
            float* st = stat + (blockIdx.x & 3) * 256;
#pragma unroll
            for (int nt = 0; nt < 4; ++nt) {
                int col = wc + nt * 16 + l15;
                atomicAdd(st + col, cs[nt]);
                atomicAdd(st + 128 + col, cq[nt]);
            }
        }
    }
}

extern "C" void kernel_launch(void* const* d_in, const int* in_sizes, int n_in,
                              void* d_out, int out_size, void* d_ws, size_t ws_size,
                              hipStream_t stream) {
    const float* x_in = (const float*)d_in[0];
    const float* z_in = (const float*)d_in[1];
    const int* ip1 = (const int*)d_in[2];
    const int* ip2 = (const int*)d_in[3];
    const float* qkv_w = (const float*)d_in[4];
    const float* proj_w = (const float*)d_in[5];
    const float* fc1_w = (const float*)d_in[6];
    const float* fc2_w = (const float*)d_in[7];
    const float* n1g = (const float*)d_in[8];
    const float* n1b = (const float*)d_in[9];
    const float* n2g = (const float*)d_in[10];
    const float* n2b = (const float*)d_in[11];

    char* ws = (char*)d_ws;
    float* xbuf = (float*)(ws + 0);                 // 67,108,864 B
    u16* wtb = (u16*)(ws + 67108864);               // 786,432 B
    float* stats = (float*)(ws + 67895296);         // S0..S3: 4 x 1024 floats
    float* scsh = stats + 4096;                     // 256 floats

    float* out_x = (float*)d_out;
    float* out_z = out_x + (size_t)NTOK * CDIM;

    hipMemsetAsync(stats, 0, 4096 * sizeof(float), stream);
    hipMemcpyAsync(out_z, z_in, (size_t)NTOK * 3 * sizeof(float),
                   hipMemcpyDeviceToDevice, stream);

    for (int i = 0; i < 2; ++i) {
        wtrans<<<(128 * 384 + 255) / 256, 256, 0, stream>>>(qkv_w + (size_t)i * 128 * 384,
                                                            wtb + i * 49152, 128, 384);
        wtrans<<<(128 * 128 + 255) / 256, 256, 0, stream>>>(proj_w + (size_t)i * 128 * 128,
                                                            wtb + 98304 + i * 16384, 128, 128);
        wtrans<<<(128 * 512 + 255) / 256, 256, 0, stream>>>(fc1_w + (size_t)i * 128 * 512,
                                                            wtb + 131072 + i * 65536, 128, 512);
        wtrans<<<(512 * 128 + 255) / 256, 256, 0, stream>>>(fc2_w + (size_t)i * 512 * 128,
                                                            wtb + 262144 + i * 65536, 512, 128);
    }

    bn_init<<<1024, 256, 0, stream>>>(x_in, stats + 0);   // S0 = bn1 stats block 0

    for (int i = 0; i < 2; ++i) {
        const int* ip = (i == 0) ? ip1 : ip2;
        const float* asrc = (i == 0) ? x_in : xbuf;
        float* S_bn1 = stats + (i == 0 ? 0 : 2048);       // S0 / S2
        float* S_bn2 = stats + (i == 0 ? 1024 : 3072);    // S1 / S3
        const u16* wt_qkv = wtb + i * 49152;
        const u16* wt_proj = wtb + 98304 + i * 16384;
        const u16* wt_fc1 = wtb + 131072 + i * 65536;
        const u16* wt_fc2 = wtb + 262144 + i * 65536;

        bn_finalize<<<1, 128, 0, stream>>>(S_bn1, n1g + i * 128, n1b + i * 128, scsh);
        attn_fused<<<2048, 256, 0, stream>>>(asrc, xbuf, ip, scsh, wt_qkv, wt_proj, S_bn2);
        bn_finalize<<<1, 128, 0, stream>>>(S_bn2, n2g + i * 128, n2b + i * 128, scsh);
        mlp_fused<<<1024, 256, 0, stream>>>(xbuf, (i == 0) ? xbuf : out_x, scsh,
                                            wt_fc1, wt_fc2,
                                            (i == 0) ? (stats + 2048) : nullptr);
    }
}